// Round 1
// baseline (520.519 us; speedup 1.0000x reference)
//
#include <hip/hip_runtime.h>

typedef __attribute__((ext_vector_type(8))) short short8;
typedef __attribute__((ext_vector_type(4))) float f32x4;

#define SQ 3072
#define DM 2048
#define NHEAD 16
#define HDIM 128

__device__ __forceinline__ unsigned short f2bf(float f) {
  union { float f; unsigned int u; } un; un.f = f;
  unsigned int r = un.u + 0x7fffu + ((un.u >> 16) & 1u);
  return (unsigned short)(r >> 16);
}

__device__ __forceinline__ void gload_lds16(const void* g, void* l) {
  __builtin_amdgcn_global_load_lds(
      (const __attribute__((address_space(1))) void*)g,
      (__attribute__((address_space(3))) void*)l, 16, 0, 0);
}

// ---------------- f32 -> bf16 convert ----------------
__global__ __launch_bounds__(256) void cvt_bf16(const float* __restrict__ in,
                                                unsigned short* __restrict__ out, int n) {
  int i = (blockIdx.x * 256 + threadIdx.x) * 8;
  if (i >= n) return;
  float4 a = *(const float4*)(in + i);
  float4 b = *(const float4*)(in + i + 4);
  short8 r;
  r[0] = (short)f2bf(a.x); r[1] = (short)f2bf(a.y);
  r[2] = (short)f2bf(a.z); r[3] = (short)f2bf(a.w);
  r[4] = (short)f2bf(b.x); r[5] = (short)f2bf(b.y);
  r[6] = (short)f2bf(b.z); r[7] = (short)f2bf(b.w);
  *(short8*)(out + i) = r;
}

// ---------------- bf16 NT GEMM + bias -> f32 ----------------
// C[M][N] = A[M][K] * B[N][K]^T + bias[N]   (M,N mult of 128; K mult of 64)
__global__ __launch_bounds__(256) void gemm_nt_bias(
    const unsigned short* __restrict__ A, const unsigned short* __restrict__ B,
    const float* __restrict__ bias, float* __restrict__ C, int M, int N, int K)
{
  __shared__ __align__(16) unsigned short As[128 * 64];
  __shared__ __align__(16) unsigned short Bs[128 * 64];
  const int tid = threadIdx.x;
  const int wave = tid >> 6, lane = tid & 63;
  const int wm = wave >> 1, wn = wave & 1;
  const int m0 = blockIdx.y * 128, n0 = blockIdx.x * 128;
  const int lr = lane & 15, lg = lane >> 4;
  const int srow = lane >> 3, scol = (lane & 7) * 8;
  f32x4 acc[4][4] = {};
  for (int k0 = 0; k0 < K; k0 += 64) {
    #pragma unroll
    for (int i = 0; i < 4; ++i) {
      int rg = i * 4 + wave;           // 16 row-groups of 8 rows
      int r = rg * 8 + srow;
      gload_lds16(A + (size_t)(m0 + r) * K + k0 + scol, &As[rg * 512]);
      gload_lds16(B + (size_t)(n0 + r) * K + k0 + scol, &Bs[rg * 512]);
    }
    __syncthreads();
    #pragma unroll
    for (int kk = 0; kk < 2; ++kk) {
      short8 af[4], bfr[4];
      #pragma unroll
      for (int m = 0; m < 4; ++m)
        af[m] = *(const short8*)&As[(wm * 64 + m * 16 + lr) * 64 + kk * 32 + lg * 8];
      #pragma unroll
      for (int n = 0; n < 4; ++n)
        bfr[n] = *(const short8*)&Bs[(wn * 64 + n * 16 + lr) * 64 + kk * 32 + lg * 8];
      #pragma unroll
      for (int m = 0; m < 4; ++m) {
        #pragma unroll
        for (int n = 0; n < 4; ++n)
          acc[m][n] = __builtin_amdgcn_mfma_f32_16x16x32_bf16(af[m], bfr[n], acc[m][n], 0, 0, 0);
      }
    }
    __syncthreads();
  }
  #pragma unroll
  for (int n = 0; n < 4; ++n) {
    int col = n0 + wn * 64 + n * 16 + lr;
    float bv = bias[col];
    #pragma unroll
    for (int m = 0; m < 4; ++m) {
      int row = m0 + wm * 64 + m * 16 + lg * 4;
      #pragma unroll
      for (int j = 0; j < 4; ++j)
        C[(size_t)(row + j) * N + col] = acc[m][n][j] + bv;
    }
  }
}

// ---------------- RMSNorm + RoPE + scale -> bf16 [head][S][128] ----------------
__global__ __launch_bounds__(256) void normrope(
    const float* __restrict__ qkv, const float* __restrict__ nqw, const float* __restrict__ nkw,
    const float* __restrict__ cosb, const float* __restrict__ sinb,
    unsigned short* __restrict__ Qb, unsigned short* __restrict__ Kb)
{
  const int s = blockIdx.x, z = blockIdx.y;  // z: 0=q, 1=k
  const float* row = qkv + ((size_t)z * SQ + s) * DM;
  const float* gw = z ? nkw : nqw;
  unsigned short* ob = z ? Kb : Qb;
  const int t = threadIdx.x;
  float v[8];
  {
    float4 a = *(const float4*)(row + t * 8);
    float4 b = *(const float4*)(row + t * 8 + 4);
    v[0] = a.x; v[1] = a.y; v[2] = a.z; v[3] = a.w;
    v[4] = b.x; v[5] = b.y; v[6] = b.z; v[7] = b.w;
  }
  float ss = 0.f;
  #pragma unroll
  for (int i = 0; i < 8; ++i) ss += v[i] * v[i];
  #pragma unroll
  for (int off = 1; off < 64; off <<= 1) ss += __shfl_xor(ss, off);
  __shared__ float red[4];
  const int wave = t >> 6, lane = t & 63;
  if (lane == 0) red[wave] = ss;
  __syncthreads();
  float tot = red[0] + red[1] + red[2] + red[3];
  float rsc = rsqrtf(tot * (1.0f / 2048.0f) + 1e-6f);
  const float qs = z ? 1.0f : 0.08838834764831845f;  // fold 1/sqrt(D) into Q
  const int col = t * 8, d = col & 127, h = col >> 7;
  const float* cb = cosb + (size_t)s * HDIM + d;
  const float* sb = sinb + (size_t)s * HDIM + d;
  float y[8];
  #pragma unroll
  for (int i = 0; i < 8; ++i) y[i] = v[i] * rsc * gw[col + i];
  short8 r;
  #pragma unroll
  for (int p = 0; p < 4; ++p) {
    float e = y[2 * p], o = y[2 * p + 1];
    float c0 = cb[2 * p], s0 = sb[2 * p];
    float c1 = cb[2 * p + 1], s1 = sb[2 * p + 1];
    r[2 * p]     = (short)f2bf((e * c0 - o * s0) * qs);
    r[2 * p + 1] = (short)f2bf((o * c1 + e * s1) * qs);
  }
  *(short8*)(ob + ((size_t)h * SQ + s) * HDIM + d) = r;
}

// ---------------- V transpose: f32 [S][2048] -> bf16 [head][128][S] ----------------
__global__ __launch_bounds__(256) void vtrans(const float* __restrict__ V,
                                              unsigned short* __restrict__ Vt)
{
  __shared__ float tile[64][65];
  const int db = blockIdx.x * 64, sb = blockIdx.y * 64, h = blockIdx.z;
  const int t = threadIdx.x;
  const int rr = t >> 2, c0 = (t & 3) * 16;
  const float* src = V + ((size_t)(sb + rr)) * DM + h * HDIM + db + c0;
  #pragma unroll
  for (int i = 0; i < 4; ++i) {
    float4 a = *(const float4*)(src + i * 4);
    tile[rr][c0 + i * 4 + 0] = a.x; tile[rr][c0 + i * 4 + 1] = a.y;
    tile[rr][c0 + i * 4 + 2] = a.z; tile[rr][c0 + i * 4 + 3] = a.w;
  }
  __syncthreads();
  const int dr = t >> 2, s0 = (t & 3) * 16;
  short8 r0, r1;
  #pragma unroll
  for (int i = 0; i < 8; ++i) r0[i] = (short)f2bf(tile[s0 + i][dr]);
  #pragma unroll
  for (int i = 0; i < 8; ++i) r1[i] = (short)f2bf(tile[s0 + 8 + i][dr]);
  unsigned short* dst = Vt + ((size_t)h * HDIM + db + dr) * SQ + sb + s0;
  *(short8*)(dst) = r0;
  *(short8*)(dst + 8) = r1;
}

// ---------------- flash attention, bf16 MFMA ----------------
// Qb/Kb: [16][S][128] bf16 (Q pre-scaled by 1/sqrt(D)); Vt: [16][128][S] bf16
// aout: [S][2048] bf16
__global__ __launch_bounds__(256) void attn(
    const unsigned short* __restrict__ Qb, const unsigned short* __restrict__ Kb,
    const unsigned short* __restrict__ Vt, const int* __restrict__ seq_lens,
    unsigned short* __restrict__ aout)
{
  __shared__ __align__(16) unsigned short Ks[64 * 136];   // [64 keys][128+8 d]
  __shared__ __align__(16) unsigned short Vs[128 * 72];   // [128 d][64+8 keys]
  __shared__ __align__(16) unsigned short Ps[4][16 * 72]; // per-wave [16 q][64+8 keys]
  const int tid = threadIdx.x, wave = tid >> 6, lane = tid & 63;
  const int h = blockIdx.y, q0 = blockIdx.x * 64;
  const int lr = lane & 15, lg = lane >> 4;
  const int seq_len = seq_lens[0];

  short8 qf[4];
  {
    const unsigned short* qrow = Qb + ((size_t)h * SQ + q0 + wave * 16 + lr) * HDIM;
    #pragma unroll
    for (int kk = 0; kk < 4; ++kk)
      qf[kk] = *(const short8*)(qrow + kk * 32 + lg * 8);
  }
  f32x4 o[8] = {};
  float mrow[4], lrow[4];
  #pragma unroll
  for (int j = 0; j < 4; ++j) { mrow[j] = -3.0e38f; lrow[j] = 0.f; }

  for (int kt = 0; kt < seq_len; kt += 64) {
    // stage K tile (reg->LDS, padded rows)
    #pragma unroll
    for (int c = 0; c < 4; ++c) {
      int lin = c * 256 + tid;
      int krow = lin >> 4, kc = (lin & 15) * 8;
      short8 tv = *(const short8*)(Kb + ((size_t)h * SQ + kt + krow) * HDIM + kc);
      *(short8*)&Ks[krow * 136 + kc] = tv;
    }
    // stage V^T tile
    #pragma unroll
    for (int c = 0; c < 4; ++c) {
      int lin = c * 256 + tid;
      int vrow = lin >> 3, vc = (lin & 7) * 8;
      short8 tv = *(const short8*)(Vt + ((size_t)h * HDIM + vrow) * SQ + kt + vc);
      *(short8*)&Vs[vrow * 72 + vc] = tv;
    }
    __syncthreads();

    // QK^T: S[16q][64keys] per wave
    f32x4 sf[4] = {};
    #pragma unroll
    for (int kk = 0; kk < 4; ++kk) {
      #pragma unroll
      for (int n = 0; n < 4; ++n) {
        short8 kf = *(const short8*)&Ks[(n * 16 + lr) * 136 + kk * 32 + lg * 8];
        sf[n] = __builtin_amdgcn_mfma_f32_16x16x32_bf16(qf[kk], kf, sf[n], 0, 0, 0);
      }
    }
    // tail-tile key masking
    if (kt + 64 > seq_len) {
      #pragma unroll
      for (int n = 0; n < 4; ++n) {
        if (kt + n * 16 + lr >= seq_len) {
          #pragma unroll
          for (int j = 0; j < 4; ++j) sf[n][j] = -3.0e38f;
        }
      }
    }
    // online softmax (row r = lg*4+j lives in 16-lane group lg)
    float tmax[4];
    #pragma unroll
    for (int j = 0; j < 4; ++j)
      tmax[j] = fmaxf(fmaxf(sf[0][j], sf[1][j]), fmaxf(sf[2][j], sf[3][j]));
    #pragma unroll
    for (int off = 1; off < 16; off <<= 1) {
      #pragma unroll
      for (int j = 0; j < 4; ++j) tmax[j] = fmaxf(tmax[j], __shfl_xor(tmax[j], off));
    }
    float alpha[4];
    #pragma unroll
    for (int j = 0; j < 4; ++j) {
      float mn = fmaxf(mrow[j], tmax[j]);
      alpha[j] = __expf(mrow[j] - mn);
      mrow[j] = mn;
    }
    float rsum[4] = {0.f, 0.f, 0.f, 0.f};
    #pragma unroll
    for (int n = 0; n < 4; ++n) {
      #pragma unroll
      for (int j = 0; j < 4; ++j) {
        float p = __expf(sf[n][j] - mrow[j]);
        sf[n][j] = p;
        rsum[j] += p;
      }
    }
    #pragma unroll
    for (int off = 1; off < 16; off <<= 1) {
      #pragma unroll
      for (int j = 0; j < 4; ++j) rsum[j] += __shfl_xor(rsum[j], off);
    }
    #pragma unroll
    for (int j = 0; j < 4; ++j) lrow[j] = lrow[j] * alpha[j] + rsum[j];
    #pragma unroll
    for (int dn = 0; dn < 8; ++dn) {
      #pragma unroll
      for (int j = 0; j < 4; ++j) o[dn][j] *= alpha[j];
    }
    // P (D-layout) -> per-wave LDS -> A-operand layout
    unsigned short* Pw = &Ps[wave][0];
    #pragma unroll
    for (int n = 0; n < 4; ++n) {
      #pragma unroll
      for (int j = 0; j < 4; ++j)
        Pw[(lg * 4 + j) * 72 + n * 16 + lr] = f2bf(sf[n][j]);
    }
    // PV: O += P[16q x 64k] * V[64k x 128d]
    #pragma unroll
    for (int kk = 0; kk < 2; ++kk) {
      short8 pa = *(const short8*)&Pw[lr * 72 + kk * 32 + lg * 8];
      #pragma unroll
      for (int dn = 0; dn < 8; ++dn) {
        short8 vb = *(const short8*)&Vs[(dn * 16 + lr) * 72 + kk * 32 + lg * 8];
        o[dn] = __builtin_amdgcn_mfma_f32_16x16x32_bf16(pa, vb, o[dn], 0, 0, 0);
      }
    }
    __syncthreads();
  }
  float rcp[4];
  #pragma unroll
  for (int j = 0; j < 4; ++j) rcp[j] = 1.0f / lrow[j];
  #pragma unroll
  for (int dn = 0; dn < 8; ++dn) {
    int col = h * HDIM + dn * 16 + lr;
    #pragma unroll
    for (int j = 0; j < 4; ++j) {
      int row = q0 + wave * 16 + lg * 4 + j;
      aout[(size_t)row * DM + col] = f2bf(o[dn][j] * rcp[j]);
    }
  }
}

extern "C" void kernel_launch(void* const* d_in, const int* in_sizes, int n_in,
                              void* d_out, int out_size, void* d_ws, size_t ws_size,
                              hipStream_t stream) {
  const float* x   = (const float*)d_in[0];
  const float* Wq  = (const float*)d_in[1];
  const float* bq  = (const float*)d_in[2];
  const float* Wk  = (const float*)d_in[3];
  const float* bk  = (const float*)d_in[4];
  const float* Wv  = (const float*)d_in[5];
  const float* bv  = (const float*)d_in[6];
  const float* Wo  = (const float*)d_in[7];
  const float* bo  = (const float*)d_in[8];
  const float* nqw = (const float*)d_in[9];
  const float* nkw = (const float*)d_in[10];
  const float* rc  = (const float*)d_in[11];
  const float* rs  = (const float*)d_in[12];
  const int* seql  = (const int*)d_in[13];
  float* out = (float*)d_out;

  // workspace layout (bytes): all 16B-aligned
  unsigned short* xb  = (unsigned short*)d_ws;              // S*DM bf16
  unsigned short* Wqb = xb  + (size_t)SQ * DM;
  unsigned short* Wkb = Wqb + (size_t)DM * DM;
  unsigned short* Wvb = Wkb + (size_t)DM * DM;
  unsigned short* Wob = Wvb + (size_t)DM * DM;
  float* qkv          = (float*)(Wob + (size_t)DM * DM);    // [3][S][DM] f32
  unsigned short* Qb  = (unsigned short*)(qkv + (size_t)3 * SQ * DM);
  unsigned short* Kb  = Qb + (size_t)SQ * DM;
  unsigned short* Vt  = Kb + (size_t)SQ * DM;
  unsigned short* aob = Vt + (size_t)SQ * DM;               // attn out bf16 [S][DM]

  const int nx = SQ * DM, nw = DM * DM;
  cvt_bf16<<<nx / 2048, 256, 0, stream>>>(x, xb, nx);
  cvt_bf16<<<nw / 2048, 256, 0, stream>>>(Wq, Wqb, nw);
  cvt_bf16<<<nw / 2048, 256, 0, stream>>>(Wk, Wkb, nw);
  cvt_bf16<<<nw / 2048, 256, 0, stream>>>(Wv, Wvb, nw);
  cvt_bf16<<<nw / 2048, 256, 0, stream>>>(Wo, Wob, nw);

  dim3 gg(DM / 128, SQ / 128);
  gemm_nt_bias<<<gg, 256, 0, stream>>>(xb, Wqb, bq, qkv + 0 * (size_t)SQ * DM, SQ, DM, DM);
  gemm_nt_bias<<<gg, 256, 0, stream>>>(xb, Wkb, bk, qkv + 1 * (size_t)SQ * DM, SQ, DM, DM);
  gemm_nt_bias<<<gg, 256, 0, stream>>>(xb, Wvb, bv, qkv + 2 * (size_t)SQ * DM, SQ, DM, DM);

  normrope<<<dim3(SQ, 2), 256, 0, stream>>>(qkv, nqw, nkw, rc, rs, Qb, Kb);
  vtrans<<<dim3(2, SQ / 64, NHEAD), 256, 0, stream>>>(qkv + 2 * (size_t)SQ * DM, Vt);

  attn<<<dim3(SQ / 64, NHEAD), 256, 0, stream>>>(Qb, Kb, Vt, seql, aob);

  gemm_nt_bias<<<gg, 256, 0, stream>>>(aob, Wob, bo, out, SQ, DM, DM);
}

// Round 2
// 467.743 us; speedup vs baseline: 1.1128x; 1.1128x over previous
//
#include <hip/hip_runtime.h>

typedef __attribute__((ext_vector_type(8))) short short8;
typedef __attribute__((ext_vector_type(4))) float f32x4;

#define SQ 3072
#define DM 2048
#define NHEAD 16
#define HDIM 128

__device__ __forceinline__ unsigned short f2bf(float f) {
  union { float f; unsigned int u; } un; un.f = f;
  unsigned int r = un.u + 0x7fffu + ((un.u >> 16) & 1u);
  return (unsigned short)(r >> 16);
}

__device__ __forceinline__ void gload_lds16(const void* g, void* l) {
  __builtin_amdgcn_global_load_lds(
      (const __attribute__((address_space(1))) void*)g,
      (__attribute__((address_space(3))) void*)l, 16, 0, 0);
}

// ---------------- f32 -> bf16 convert ----------------
__global__ __launch_bounds__(256) void cvt_bf16(const float* __restrict__ in,
                                                unsigned short* __restrict__ out, int n) {
  int i = (blockIdx.x * 256 + threadIdx.x) * 8;
  if (i >= n) return;
  float4 a = *(const float4*)(in + i);
  float4 b = *(const float4*)(in + i + 4);
  short8 r;
  r[0] = (short)f2bf(a.x); r[1] = (short)f2bf(a.y);
  r[2] = (short)f2bf(a.z); r[3] = (short)f2bf(a.w);
  r[4] = (short)f2bf(b.x); r[5] = (short)f2bf(b.y);
  r[6] = (short)f2bf(b.z); r[7] = (short)f2bf(b.w);
  *(short8*)(out + i) = r;
}

// ---------------- bf16 NT GEMM + bias -> f32 ----------------
// C[M][N] = A[M][K] * B[N][K]^T + bias   (M,N mult of 128; K mult of 64)
// bias segment selected per 2048-col segment (b0/b1/b2).
__global__ __launch_bounds__(256) void gemm_nt_bias(
    const unsigned short* __restrict__ A, const unsigned short* __restrict__ B,
    const float* __restrict__ b0, const float* __restrict__ b1, const float* __restrict__ b2,
    float* __restrict__ C, int M, int N, int K)
{
  __shared__ __align__(16) unsigned short As[128 * 64];
  __shared__ __align__(16) unsigned short Bs[128 * 64];
  const int tid = threadIdx.x;
  const int wave = tid >> 6, lane = tid & 63;
  const int wm = wave >> 1, wn = wave & 1;
  const int m0 = blockIdx.y * 128, n0 = blockIdx.x * 128;
  const int lr = lane & 15, lg = lane >> 4;
  const int srow = lane >> 3, scol = (lane & 7) * 8;
  f32x4 acc[4][4] = {};
  for (int k0 = 0; k0 < K; k0 += 64) {
    #pragma unroll
    for (int i = 0; i < 4; ++i) {
      int rg = i * 4 + wave;           // 16 row-groups of 8 rows
      int r = rg * 8 + srow;
      gload_lds16(A + (size_t)(m0 + r) * K + k0 + scol, &As[rg * 512]);
      gload_lds16(B + (size_t)(n0 + r) * K + k0 + scol, &Bs[rg * 512]);
    }
    __syncthreads();
    #pragma unroll
    for (int kk = 0; kk < 2; ++kk) {
      short8 af[4], bfr[4];
      #pragma unroll
      for (int m = 0; m < 4; ++m)
        af[m] = *(const short8*)&As[(wm * 64 + m * 16 + lr) * 64 + kk * 32 + lg * 8];
      #pragma unroll
      for (int n = 0; n < 4; ++n)
        bfr[n] = *(const short8*)&Bs[(wn * 64 + n * 16 + lr) * 64 + kk * 32 + lg * 8];
      #pragma unroll
      for (int m = 0; m < 4; ++m) {
        #pragma unroll
        for (int n = 0; n < 4; ++n)
          acc[m][n] = __builtin_amdgcn_mfma_f32_16x16x32_bf16(af[m], bfr[n], acc[m][n], 0, 0, 0);
      }
    }
    __syncthreads();
  }
  const float* bp = (n0 < DM) ? b0 : ((n0 < 2 * DM) ? b1 : b2);
  #pragma unroll
  for (int n = 0; n < 4; ++n) {
    int col = n0 + wn * 64 + n * 16 + lr;
    float bv = bp[col & (DM - 1)];
    #pragma unroll
    for (int m = 0; m < 4; ++m) {
      int row = m0 + wm * 64 + m * 16 + lg * 4;
      #pragma unroll
      for (int j = 0; j < 4; ++j)
        C[(size_t)(row + j) * N + col] = acc[m][n][j] + bv;
    }
  }
}

// ---------------- RMSNorm + RoPE + scale -> bf16 [head][S][128] ----------------
// qkv layout: [S][3*DM] f32.  Q gets log2(e)/sqrt(D) folded in.
__global__ __launch_bounds__(256) void normrope(
    const float* __restrict__ qkv, const float* __restrict__ nqw, const float* __restrict__ nkw,
    const float* __restrict__ cosb, const float* __restrict__ sinb,
    unsigned short* __restrict__ Qb, unsigned short* __restrict__ Kb)
{
  const int s = blockIdx.x, z = blockIdx.y;  // z: 0=q, 1=k
  const float* row = qkv + ((size_t)s * 3 + z) * DM;
  const float* gw = z ? nkw : nqw;
  unsigned short* ob = z ? Kb : Qb;
  const int t = threadIdx.x;
  float v[8];
  {
    float4 a = *(const float4*)(row + t * 8);
    float4 b = *(const float4*)(row + t * 8 + 4);
    v[0] = a.x; v[1] = a.y; v[2] = a.z; v[3] = a.w;
    v[4] = b.x; v[5] = b.y; v[6] = b.z; v[7] = b.w;
  }
  float ss = 0.f;
  #pragma unroll
  for (int i = 0; i < 8; ++i) ss += v[i] * v[i];
  #pragma unroll
  for (int off = 1; off < 64; off <<= 1) ss += __shfl_xor(ss, off);
  __shared__ float red[4];
  const int wave = t >> 6, lane = t & 63;
  if (lane == 0) red[wave] = ss;
  __syncthreads();
  float tot = red[0] + red[1] + red[2] + red[3];
  float rsc = rsqrtf(tot * (1.0f / 2048.0f) + 1e-6f);
  // Q: fold log2(e)/sqrt(D) so attention can use exp2 with no per-elem scale
  const float qs = z ? 1.0f : 0.12751879522087045f;
  const int col = t * 8, d = col & 127, h = col >> 7;
  const float* cb = cosb + (size_t)s * HDIM + d;
  const float* sb = sinb + (size_t)s * HDIM + d;
  float y[8];
  #pragma unroll
  for (int i = 0; i < 8; ++i) y[i] = v[i] * rsc * gw[col + i];
  short8 r;
  #pragma unroll
  for (int p = 0; p < 4; ++p) {
    float e = y[2 * p], o = y[2 * p + 1];
    float c0 = cb[2 * p], s0 = sb[2 * p];
    float c1 = cb[2 * p + 1], s1 = sb[2 * p + 1];
    r[2 * p]     = (short)f2bf((e * c0 - o * s0) * qs);
    r[2 * p + 1] = (short)f2bf((o * c1 + e * s1) * qs);
  }
  *(short8*)(ob + ((size_t)h * SQ + s) * HDIM + d) = r;
}

// ---------------- V transpose: f32 [S][ldv] -> bf16 [head][128][S] ----------------
__global__ __launch_bounds__(256) void vtrans(const float* __restrict__ V, int ldv,
                                              unsigned short* __restrict__ Vt)
{
  __shared__ float tile[64][65];
  const int db = blockIdx.x * 64, sb = blockIdx.y * 64, h = blockIdx.z;
  const int t = threadIdx.x;
  const int rr = t >> 2, c0 = (t & 3) * 16;
  const float* src = V + (size_t)(sb + rr) * ldv + h * HDIM + db + c0;
  #pragma unroll
  for (int i = 0; i < 4; ++i) {
    float4 a = *(const float4*)(src + i * 4);
    tile[rr][c0 + i * 4 + 0] = a.x; tile[rr][c0 + i * 4 + 1] = a.y;
    tile[rr][c0 + i * 4 + 2] = a.z; tile[rr][c0 + i * 4 + 3] = a.w;
  }
  __syncthreads();
  const int dr = t >> 2, s0 = (t & 3) * 16;
  short8 r0, r1;
  #pragma unroll
  for (int i = 0; i < 8; ++i) r0[i] = (short)f2bf(tile[s0 + i][dr]);
  #pragma unroll
  for (int i = 0; i < 8; ++i) r1[i] = (short)f2bf(tile[s0 + 8 + i][dr]);
  unsigned short* dst = Vt + ((size_t)h * HDIM + db + dr) * SQ + sb + s0;
  *(short8*)(dst) = r0;
  *(short8*)(dst + 8) = r1;
}

// ---------------- flash attention (no-max softmax), bf16 MFMA ----------------
// Scores are bounded (RMS-normed q,k => |s| <= sqrt(D) ~ 11.3), so skip the
// row-max entirely: p = exp2(s'), s' pre-scaled by log2(e)/sqrt(D) in Q.
// Row-sum accumulated per-lane across tiles; single shuffle reduce at end.
__global__ __launch_bounds__(256) void attn(
    const unsigned short* __restrict__ Qb, const unsigned short* __restrict__ Kb,
    const unsigned short* __restrict__ Vt, const int* __restrict__ seq_lens,
    unsigned short* __restrict__ aout)
{
  __shared__ __align__(16) unsigned short Ks[64 * 136];   // [64 keys][128+8 d]
  __shared__ __align__(16) unsigned short Vs[128 * 72];   // [128 d][64+8 keys]
  __shared__ __align__(16) unsigned short Ps[4][16 * 72]; // per-wave [16 q][64+8 keys]
  const int tid = threadIdx.x, wave = tid >> 6, lane = tid & 63;
  const int h = blockIdx.y, q0 = blockIdx.x * 64;
  const int lr = lane & 15, lg = lane >> 4;
  const int seq_len = seq_lens[0];

  short8 qf[4];
  {
    const unsigned short* qrow = Qb + ((size_t)h * SQ + q0 + wave * 16 + lr) * HDIM;
    #pragma unroll
    for (int kk = 0; kk < 4; ++kk)
      qf[kk] = *(const short8*)(qrow + kk * 32 + lg * 8);
  }
  f32x4 o[8] = {};
  float lsum[4] = {0.f, 0.f, 0.f, 0.f};

  for (int kt = 0; kt < seq_len; kt += 64) {
    // stage K tile (reg->LDS, padded rows)
    #pragma unroll
    for (int c = 0; c < 4; ++c) {
      int lin = c * 256 + tid;
      int krow = lin >> 4, kc = (lin & 15) * 8;
      short8 tv = *(const short8*)(Kb + ((size_t)h * SQ + kt + krow) * HDIM + kc);
      *(short8*)&Ks[krow * 136 + kc] = tv;
    }
    // stage V^T tile
    #pragma unroll
    for (int c = 0; c < 4; ++c) {
      int lin = c * 256 + tid;
      int vrow = lin >> 3, vc = (lin & 7) * 8;
      short8 tv = *(const short8*)(Vt + ((size_t)h * HDIM + vrow) * SQ + kt + vc);
      *(short8*)&Vs[vrow * 72 + vc] = tv;
    }
    __syncthreads();

    // QK^T: S[16q][64keys] per wave
    f32x4 sf[4] = {};
    #pragma unroll
    for (int kk = 0; kk < 4; ++kk) {
      #pragma unroll
      for (int n = 0; n < 4; ++n) {
        short8 kf = *(const short8*)&Ks[(n * 16 + lr) * 136 + kk * 32 + lg * 8];
        sf[n] = __builtin_amdgcn_mfma_f32_16x16x32_bf16(qf[kk], kf, sf[n], 0, 0, 0);
      }
    }
    // tail-tile key masking
    if (kt + 64 > seq_len) {
      #pragma unroll
      for (int n = 0; n < 4; ++n) {
        if (kt + n * 16 + lr >= seq_len) {
          #pragma unroll
          for (int j = 0; j < 4; ++j) sf[n][j] = -3.0e38f;
        }
      }
    }
    // p = exp2(s'); accumulate per-lane row-sum; stash bf16 P in per-wave LDS
    unsigned short* Pw = &Ps[wave][0];
    #pragma unroll
    for (int n = 0; n < 4; ++n) {
      #pragma unroll
      for (int j = 0; j < 4; ++j) {
        float p = exp2f(sf[n][j]);
        lsum[j] += p;
        Pw[(lg * 4 + j) * 72 + n * 16 + lr] = f2bf(p);
      }
    }
    // PV: O += P[16q x 64k] * V[64k x 128d]
    #pragma unroll
    for (int kk = 0; kk < 2; ++kk) {
      short8 pa = *(const short8*)&Pw[lr * 72 + kk * 32 + lg * 8];
      #pragma unroll
      for (int dn = 0; dn < 8; ++dn) {
        short8 vb = *(const short8*)&Vs[(dn * 16 + lr) * 72 + kk * 32 + lg * 8];
        o[dn] = __builtin_amdgcn_mfma_f32_16x16x32_bf16(pa, vb, o[dn], 0, 0, 0);
      }
    }
    __syncthreads();
  }
  // one final row-sum reduce across the 16-lane column group
  #pragma unroll
  for (int off = 1; off < 16; off <<= 1) {
    #pragma unroll
    for (int j = 0; j < 4; ++j) lsum[j] += __shfl_xor(lsum[j], off);
  }
  float rcp[4];
  #pragma unroll
  for (int j = 0; j < 4; ++j) rcp[j] = 1.0f / lsum[j];
  #pragma unroll
  for (int dn = 0; dn < 8; ++dn) {
    int col = h * HDIM + dn * 16 + lr;
    #pragma unroll
    for (int j = 0; j < 4; ++j) {
      int row = q0 + wave * 16 + lg * 4 + j;
      aout[(size_t)row * DM + col] = f2bf(o[dn][j] * rcp[j]);
    }
  }
}

extern "C" void kernel_launch(void* const* d_in, const int* in_sizes, int n_in,
                              void* d_out, int out_size, void* d_ws, size_t ws_size,
                              hipStream_t stream) {
  const float* x   = (const float*)d_in[0];
  const float* Wq  = (const float*)d_in[1];
  const float* bq  = (const float*)d_in[2];
  const float* Wk  = (const float*)d_in[3];
  const float* bk  = (const float*)d_in[4];
  const float* Wv  = (const float*)d_in[5];
  const float* bv  = (const float*)d_in[6];
  const float* Wo  = (const float*)d_in[7];
  const float* bo  = (const float*)d_in[8];
  const float* nqw = (const float*)d_in[9];
  const float* nkw = (const float*)d_in[10];
  const float* rc  = (const float*)d_in[11];
  const float* rs  = (const float*)d_in[12];
  const int* seql  = (const int*)d_in[13];
  float* out = (float*)d_out;

  // workspace layout: all 16B-aligned
  unsigned short* xb   = (unsigned short*)d_ws;             // S*DM bf16
  unsigned short* Wqkv = xb   + (size_t)SQ * DM;            // [3*DM][DM] bf16
  unsigned short* Wob  = Wqkv + (size_t)3 * DM * DM;
  float* qkv           = (float*)(Wob + (size_t)DM * DM);   // [S][3*DM] f32
  unsigned short* Qb   = (unsigned short*)(qkv + (size_t)3 * SQ * DM);
  unsigned short* Kb   = Qb + (size_t)SQ * DM;
  unsigned short* Vt   = Kb + (size_t)SQ * DM;
  unsigned short* aob  = Vt + (size_t)SQ * DM;              // attn out bf16 [S][DM]

  const int nx = SQ * DM, nw = DM * DM;
  cvt_bf16<<<nx / 2048, 256, 0, stream>>>(x, xb, nx);
  cvt_bf16<<<nw / 2048, 256, 0, stream>>>(Wq, Wqkv, nw);
  cvt_bf16<<<nw / 2048, 256, 0, stream>>>(Wk, Wqkv + (size_t)nw, nw);
  cvt_bf16<<<nw / 2048, 256, 0, stream>>>(Wv, Wqkv + (size_t)2 * nw, nw);
  cvt_bf16<<<nw / 2048, 256, 0, stream>>>(Wo, Wob, nw);

  // fused QKV GEMM: [S][3*DM] = xb * Wqkv^T
  dim3 gq(3 * DM / 128, SQ / 128);
  gemm_nt_bias<<<gq, 256, 0, stream>>>(xb, Wqkv, bq, bk, bv, qkv, SQ, 3 * DM, DM);

  normrope<<<dim3(SQ, 2), 256, 0, stream>>>(qkv, nqw, nkw, rc, rs, Qb, Kb);
  vtrans<<<dim3(2, SQ / 64, NHEAD), 256, 0, stream>>>(qkv + 2 * DM, 3 * DM, Vt);

  attn<<<dim3(SQ / 64, NHEAD), 256, 0, stream>>>(Qb, Kb, Vt, seql, aob);

  dim3 go(DM / 128, SQ / 128);
  gemm_nt_bias<<<go, 256, 0, stream>>>(aob, Wob, bo, bo, bo, out, SQ, DM, DM);
}

// Round 3
// 429.829 us; speedup vs baseline: 1.2110x; 1.0882x over previous
//
#include <hip/hip_runtime.h>

typedef __attribute__((ext_vector_type(8))) short short8;
typedef __attribute__((ext_vector_type(4))) float f32x4;

#define SQ 3072
#define DM 2048
#define NHEAD 16
#define HDIM 128

__device__ __forceinline__ unsigned short f2bf(float f) {
  union { float f; unsigned int u; } un; un.f = f;
  unsigned int r = un.u + 0x7fffu + ((un.u >> 16) & 1u);
  return (unsigned short)(r >> 16);
}

__device__ __forceinline__ void gload_lds16(const void* g, void* l) {
  __builtin_amdgcn_global_load_lds(
      (const __attribute__((address_space(1))) void*)g,
      (__attribute__((address_space(3))) void*)l, 16, 0, 0);
}

// ---------------- fused f32 -> bf16 convert (x, Wq, Wk, Wv, Wo) ----------------
__global__ __launch_bounds__(256) void cvt_all(
    const float* __restrict__ x, const float* __restrict__ wq, const float* __restrict__ wk,
    const float* __restrict__ wv, const float* __restrict__ wo,
    unsigned short* __restrict__ xb, unsigned short* __restrict__ wqkvb,
    unsigned short* __restrict__ wob)
{
  int b = blockIdx.x;
  const float* src; unsigned short* dst; int idx;
  if (b < 3072) { src = x; dst = xb; idx = b; }
  else {
    int r = b - 3072; int w = r >> 11; idx = r & 2047;
    src = (w == 0) ? wq : (w == 1) ? wk : (w == 2) ? wv : wo;
    dst = (w < 3) ? wqkvb + (size_t)w * DM * DM : wob;
  }
  int i = (idx * 256 + threadIdx.x) * 8;
  float4 a = *(const float4*)(src + i);
  float4 c = *(const float4*)(src + i + 4);
  short8 r;
  r[0] = (short)f2bf(a.x); r[1] = (short)f2bf(a.y);
  r[2] = (short)f2bf(a.z); r[3] = (short)f2bf(a.w);
  r[4] = (short)f2bf(c.x); r[5] = (short)f2bf(c.y);
  r[6] = (short)f2bf(c.z); r[7] = (short)f2bf(c.w);
  *(short8*)(dst + i) = r;
}

// ---------------- bf16 NT GEMM + bias -> f32 (3-buffer ring, counted vmcnt) ----
// C[M][N] = A[M][K] * B[N][K]^T + bias   (M,N mult of 128; K mult of 64)
// LDS: 3 ring buffers x (A 128x64 + B 128x64) bf16 = 96 KB.
// XOR-swizzle (T2): 16B slot s at row r holds k-slot s^(r&7); applied on the
// per-lane GLOBAL source address (linear global_load_lds dest, rule #21) and
// mirrored on the ds_read addresses -> 8 bank-starts/16 lanes = conflict-free.
__global__ __launch_bounds__(256) void gemm_nt_bias(
    const unsigned short* __restrict__ A, const unsigned short* __restrict__ B,
    const float* __restrict__ b0, const float* __restrict__ b1, const float* __restrict__ b2,
    float* __restrict__ C, int M, int N, int K)
{
  __shared__ __align__(16) unsigned short lds[3 * 16384];
  const int tid = threadIdx.x;
  const int wave = tid >> 6, lane = tid & 63;
  const int wm = wave >> 1, wn = wave & 1;
  const int m0 = blockIdx.y * 128, n0 = blockIdx.x * 128;
  const int lr = lane & 15, lg = lane >> 4;

  // staging precompute: thread handles row srow(+32c), swizzled k-slot ks
  const int srow = tid >> 3;
  const int ks = (tid & 7) ^ (srow & 7);
  const unsigned short* aSrc = A + (size_t)(m0 + srow) * K + ks * 8;
  const unsigned short* bSrc = B + (size_t)(n0 + srow) * K + ks * 8;
  const int dstOff = (tid & 192) * 8;  // wave-uniform LDS base (shorts)

  auto stage = [&](int t, int b) {
    const unsigned short* as = aSrc + (size_t)t * 64;
    const unsigned short* bs = bSrc + (size_t)t * 64;
    unsigned short* la = &lds[b * 16384 + dstOff];
    #pragma unroll
    for (int c = 0; c < 4; ++c) {
      gload_lds16(as + (size_t)c * 32 * K, la + c * 2048);
      gload_lds16(bs + (size_t)c * 32 * K, la + 8192 + c * 2048);
    }
  };

  f32x4 acc[4][4] = {};
  const int nt = K >> 6;
  stage(0, 0);
  stage(1, 1);
  asm volatile("s_waitcnt vmcnt(8)\n\ts_barrier" ::: "memory");

  const int sx = lr & 7;
  const int arow = wm * 64 + lr;
  const int brow = wn * 64 + lr;
  for (int t = 0; t < nt; ++t) {
    const unsigned short* La = &lds[(t % 3) * 16384];
    const unsigned short* Lb = La + 8192;
    if (t + 2 < nt) stage(t + 2, (t + 2) % 3);
    short8 af[2][4], bfr[2][4];
    #pragma unroll
    for (int kk = 0; kk < 2; ++kk) {
      #pragma unroll
      for (int m = 0; m < 4; ++m)
        af[kk][m] = *(const short8*)&La[(arow + m * 16) * 64 + (((kk * 4 + lg) ^ sx) << 3)];
      #pragma unroll
      for (int n = 0; n < 4; ++n)
        bfr[kk][n] = *(const short8*)&Lb[(brow + n * 16) * 64 + (((kk * 4 + lg) ^ sx) << 3)];
    }
    __builtin_amdgcn_s_setprio(1);
    #pragma unroll
    for (int kk = 0; kk < 2; ++kk) {
      #pragma unroll
      for (int m = 0; m < 4; ++m) {
        #pragma unroll
        for (int n = 0; n < 4; ++n)
          acc[m][n] = __builtin_amdgcn_mfma_f32_16x16x32_bf16(af[kk][m], bfr[kk][n], acc[m][n], 0, 0, 0);
      }
    }
    __builtin_amdgcn_s_setprio(0);
    if (t + 2 < nt) asm volatile("s_waitcnt vmcnt(8)\n\ts_barrier" ::: "memory");
    else            asm volatile("s_waitcnt vmcnt(0)\n\ts_barrier" ::: "memory");
  }

  const float* bp = (n0 < DM) ? b0 : ((n0 < 2 * DM) ? b1 : b2);
  #pragma unroll
  for (int n = 0; n < 4; ++n) {
    int col = n0 + wn * 64 + n * 16 + lr;
    float bv = bp[col & (DM - 1)];
    #pragma unroll
    for (int m = 0; m < 4; ++m) {
      int row = m0 + wm * 64 + m * 16 + lg * 4;
      #pragma unroll
      for (int j = 0; j < 4; ++j)
        C[(size_t)(row + j) * N + col] = acc[m][n][j] + bv;
    }
  }
}

// ---------------- RMSNorm + RoPE + scale -> bf16 [head][S][128] ----------------
// qkv layout: [S][3*DM] f32.  Q gets log2(e)/sqrt(D) folded in.
__global__ __launch_bounds__(256) void normrope(
    const float* __restrict__ qkv, const float* __restrict__ nqw, const float* __restrict__ nkw,
    const float* __restrict__ cosb, const float* __restrict__ sinb,
    unsigned short* __restrict__ Qb, unsigned short* __restrict__ Kb)
{
  const int s = blockIdx.x, z = blockIdx.y;  // z: 0=q, 1=k
  const float* row = qkv + ((size_t)s * 3 + z) * DM;
  const float* gw = z ? nkw : nqw;
  unsigned short* ob = z ? Kb : Qb;
  const int t = threadIdx.x;
  float v[8];
  {
    float4 a = *(const float4*)(row + t * 8);
    float4 b = *(const float4*)(row + t * 8 + 4);
    v[0] = a.x; v[1] = a.y; v[2] = a.z; v[3] = a.w;
    v[4] = b.x; v[5] = b.y; v[6] = b.z; v[7] = b.w;
  }
  float ss = 0.f;
  #pragma unroll
  for (int i = 0; i < 8; ++i) ss += v[i] * v[i];
  #pragma unroll
  for (int off = 1; off < 64; off <<= 1) ss += __shfl_xor(ss, off);
  __shared__ float red[4];
  const int wave = t >> 6, lane = t & 63;
  if (lane == 0) red[wave] = ss;
  __syncthreads();
  float tot = red[0] + red[1] + red[2] + red[3];
  float rsc = rsqrtf(tot * (1.0f / 2048.0f) + 1e-6f);
  const float qs = z ? 1.0f : 0.12751879522087045f;  // log2(e)/sqrt(D)
  const int col = t * 8, d = col & 127, h = col >> 7;
  const float* cb = cosb + (size_t)s * HDIM + d;
  const float* sb = sinb + (size_t)s * HDIM + d;
  float y[8];
  #pragma unroll
  for (int i = 0; i < 8; ++i) y[i] = v[i] * rsc * gw[col + i];
  short8 r;
  #pragma unroll
  for (int p = 0; p < 4; ++p) {
    float e = y[2 * p], o = y[2 * p + 1];
    float c0 = cb[2 * p], s0 = sb[2 * p];
    float c1 = cb[2 * p + 1], s1 = sb[2 * p + 1];
    r[2 * p]     = (short)f2bf((e * c0 - o * s0) * qs);
    r[2 * p + 1] = (short)f2bf((o * c1 + e * s1) * qs);
  }
  *(short8*)(ob + ((size_t)h * SQ + s) * HDIM + d) = r;
}

// ---------------- V transpose: f32 [S][ldv] -> bf16 [head][128][S] ----------------
__global__ __launch_bounds__(256) void vtrans(const float* __restrict__ V, int ldv,
                                              unsigned short* __restrict__ Vt)
{
  __shared__ float tile[64][65];
  const int db = blockIdx.x * 64, sb = blockIdx.y * 64, h = blockIdx.z;
  const int t = threadIdx.x;
  const int rr = t >> 2, c0 = (t & 3) * 16;
  const float* src = V + (size_t)(sb + rr) * ldv + h * HDIM + db + c0;
  #pragma unroll
  for (int i = 0; i < 4; ++i) {
    float4 a = *(const float4*)(src + i * 4);
    tile[rr][c0 + i * 4 + 0] = a.x; tile[rr][c0 + i * 4 + 1] = a.y;
    tile[rr][c0 + i * 4 + 2] = a.z; tile[rr][c0 + i * 4 + 3] = a.w;
  }
  __syncthreads();
  const int dr = t >> 2, s0 = (t & 3) * 16;
  short8 r0, r1;
  #pragma unroll
  for (int i = 0; i < 8; ++i) r0[i] = (short)f2bf(tile[s0 + i][dr]);
  #pragma unroll
  for (int i = 0; i < 8; ++i) r1[i] = (short)f2bf(tile[s0 + 8 + i][dr]);
  unsigned short* dst = Vt + ((size_t)h * HDIM + db + dr) * SQ + sb + s0;
  *(short8*)(dst) = r0;
  *(short8*)(dst + 8) = r1;
}

// ---------------- flash attention (no-max softmax), bf16 MFMA ----------------
__global__ __launch_bounds__(256) void attn(
    const unsigned short* __restrict__ Qb, const unsigned short* __restrict__ Kb,
    const unsigned short* __restrict__ Vt, const int* __restrict__ seq_lens,
    unsigned short* __restrict__ aout)
{
  __shared__ __align__(16) unsigned short Ks[64 * 136];   // [64 keys][128+8 d]
  __shared__ __align__(16) unsigned short Vs[128 * 72];   // [128 d][64+8 keys]
  __shared__ __align__(16) unsigned short Ps[4][16 * 72]; // per-wave [16 q][64+8 keys]
  const int tid = threadIdx.x, wave = tid >> 6, lane = tid & 63;
  const int h = blockIdx.y, q0 = blockIdx.x * 64;
  const int lr = lane & 15, lg = lane >> 4;
  const int seq_len = seq_lens[0];

  short8 qf[4];
  {
    const unsigned short* qrow = Qb + ((size_t)h * SQ + q0 + wave * 16 + lr) * HDIM;
    #pragma unroll
    for (int kk = 0; kk < 4; ++kk)
      qf[kk] = *(const short8*)(qrow + kk * 32 + lg * 8);
  }
  f32x4 o[8] = {};
  float lsum[4] = {0.f, 0.f, 0.f, 0.f};

  for (int kt = 0; kt < seq_len; kt += 64) {
    #pragma unroll
    for (int c = 0; c < 4; ++c) {
      int lin = c * 256 + tid;
      int krow = lin >> 4, kc = (lin & 15) * 8;
      short8 tv = *(const short8*)(Kb + ((size_t)h * SQ + kt + krow) * HDIM + kc);
      *(short8*)&Ks[krow * 136 + kc] = tv;
    }
    #pragma unroll
    for (int c = 0; c < 4; ++c) {
      int lin = c * 256 + tid;
      int vrow = lin >> 3, vc = (lin & 7) * 8;
      short8 tv = *(const short8*)(Vt + ((size_t)h * HDIM + vrow) * SQ + kt + vc);
      *(short8*)&Vs[vrow * 72 + vc] = tv;
    }
    __syncthreads();

    f32x4 sf[4] = {};
    #pragma unroll
    for (int kk = 0; kk < 4; ++kk) {
      #pragma unroll
      for (int n = 0; n < 4; ++n) {
        short8 kf = *(const short8*)&Ks[(n * 16 + lr) * 136 + kk * 32 + lg * 8];
        sf[n] = __builtin_amdgcn_mfma_f32_16x16x32_bf16(qf[kk], kf, sf[n], 0, 0, 0);
      }
    }
    if (kt + 64 > seq_len) {
      #pragma unroll
      for (int n = 0; n < 4; ++n) {
        if (kt + n * 16 + lr >= seq_len) {
          #pragma unroll
          for (int j = 0; j < 4; ++j) sf[n][j] = -3.0e38f;
        }
      }
    }
    unsigned short* Pw = &Ps[wave][0];
    #pragma unroll
    for (int n = 0; n < 4; ++n) {
      #pragma unroll
      for (int j = 0; j < 4; ++j) {
        float p = exp2f(sf[n][j]);
        lsum[j] += p;
        Pw[(lg * 4 + j) * 72 + n * 16 + lr] = f2bf(p);
      }
    }
    #pragma unroll
    for (int kk = 0; kk < 2; ++kk) {
      short8 pa = *(const short8*)&Pw[lr * 72 + kk * 32 + lg * 8];
      #pragma unroll
      for (int dn = 0; dn < 8; ++dn) {
        short8 vb = *(const short8*)&Vs[(dn * 16 + lr) * 72 + kk * 32 + lg * 8];
        o[dn] = __builtin_amdgcn_mfma_f32_16x16x32_bf16(pa, vb, o[dn], 0, 0, 0);
      }
    }
    __syncthreads();
  }
  #pragma unroll
  for (int off = 1; off < 16; off <<= 1) {
    #pragma unroll
    for (int j = 0; j < 4; ++j) lsum[j] += __shfl_xor(lsum[j], off);
  }
  float rcp[4];
  #pragma unroll
  for (int j = 0; j < 4; ++j) rcp[j] = 1.0f / lsum[j];
  #pragma unroll
  for (int dn = 0; dn < 8; ++dn) {
    int col = h * HDIM + dn * 16 + lr;
    #pragma unroll
    for (int j = 0; j < 4; ++j) {
      int row = q0 + wave * 16 + lg * 4 + j;
      aout[(size_t)row * DM + col] = f2bf(o[dn][j] * rcp[j]);
    }
  }
}

extern "C" void kernel_launch(void* const* d_in, const int* in_sizes, int n_in,
                              void* d_out, int out_size, void* d_ws, size_t ws_size,
                              hipStream_t stream) {
  const float* x   = (const float*)d_in[0];
  const float* Wq  = (const float*)d_in[1];
  const float* bq  = (const float*)d_in[2];
  const float* Wk  = (const float*)d_in[3];
  const float* bk  = (const float*)d_in[4];
  const float* Wv  = (const float*)d_in[5];
  const float* bv  = (const float*)d_in[6];
  const float* Wo  = (const float*)d_in[7];
  const float* bo  = (const float*)d_in[8];
  const float* nqw = (const float*)d_in[9];
  const float* nkw = (const float*)d_in[10];
  const float* rc  = (const float*)d_in[11];
  const float* rs  = (const float*)d_in[12];
  const int* seql  = (const int*)d_in[13];
  float* out = (float*)d_out;

  unsigned short* xb   = (unsigned short*)d_ws;             // S*DM bf16
  unsigned short* Wqkv = xb   + (size_t)SQ * DM;            // [3*DM][DM] bf16
  unsigned short* Wob  = Wqkv + (size_t)3 * DM * DM;
  float* qkv           = (float*)(Wob + (size_t)DM * DM);   // [S][3*DM] f32
  unsigned short* Qb   = (unsigned short*)(qkv + (size_t)3 * SQ * DM);
  unsigned short* Kb   = Qb + (size_t)SQ * DM;
  unsigned short* Vt   = Kb + (size_t)SQ * DM;
  unsigned short* aob  = Vt + (size_t)SQ * DM;              // attn out bf16 [S][DM]

  cvt_all<<<3072 + 4 * 2048, 256, 0, stream>>>(x, Wq, Wk, Wv, Wo, xb, Wqkv, Wob);

  dim3 gq(3 * DM / 128, SQ / 128);
  gemm_nt_bias<<<gq, 256, 0, stream>>>(xb, Wqkv, bq, bk, bv, qkv, SQ, 3 * DM, DM);

  normrope<<<dim3(SQ, 2), 256, 0, stream>>>(qkv, nqw, nkw, rc, rs, Qb, Kb);
  vtrans<<<dim3(2, SQ / 64, NHEAD), 256, 0, stream>>>(qkv + 2 * DM, 3 * DM, Vt);

  attn<<<dim3(SQ / 64, NHEAD), 256, 0, stream>>>(Qb, Kb, Vt, seql, aob);

  dim3 go(DM / 128, SQ / 128);
  gemm_nt_bias<<<go, 256, 0, stream>>>(aob, Wob, bo, bo, bo, out, SQ, DM, DM);
}